// Round 15
// baseline (7717.947 us; speedup 1.0000x reference)
//
#include <hip/hip_runtime.h>
#include <hip/hip_bf16.h>

#define T_ 256
#define B_ 128
#define H_ 512
#define G3 1536
#define SCH 32      // timesteps per chunk
#define NCH 8       // chunks per layer
#define RWG 32      // rec WGs per dir (8 unit-groups x 4 batch-groups)
#define BGRP 8      // producers per sync group (same dir,bg; all ug)

typedef __attribute__((ext_vector_type(8))) short short8;
typedef __attribute__((ext_vector_type(4))) short short4v;
typedef __attribute__((ext_vector_type(4))) float f32x4;
typedef __attribute__((ext_vector_type(4))) unsigned int uint4v;

static __device__ __forceinline__ float b2f(short s){
    unsigned u = ((unsigned)(unsigned short)s) << 16;
    return __builtin_bit_cast(float, u);
}
static __device__ __forceinline__ short f2b(float f){
    __hip_bfloat16 h = __float2bfloat16(f);   // RNE
    return __builtin_bit_cast(short, h);
}
static __device__ __forceinline__ void gload16(const void* g, void* l){
    __builtin_amdgcn_global_load_lds(
        (__attribute__((address_space(1))) void*)(void*)g,
        (__attribute__((address_space(3))) void*)l, 16, 0, 0);
}
static __device__ __forceinline__ void wait_vm0(){
    asm volatile("s_waitcnt vmcnt(0)" ::: "memory");
}
// device-coherent (MALL) ops — round-6-proven semantics
static __device__ __forceinline__ short8 gload_sc(const short* p){
    short8 v;
    asm volatile("global_load_dwordx4 %0, %1, off sc0 sc1"
                 : "=v"(v) : "v"(p) : "memory");
    return v;
}
static __device__ __forceinline__ void gstore16_sc(short* p, short8 v){
    asm volatile("global_store_dwordx4 %0, %1, off sc0 sc1"
                 :: "v"(p), "v"(v) : "memory");
}
static __device__ __forceinline__ void store_flag(unsigned int* p, unsigned int v){
    asm volatile("global_store_dword %0, %1, off sc0 sc1"
                 :: "v"(p), "v"(v) : "memory");
}
static __device__ __forceinline__ unsigned int poll_dw(const unsigned int* p){
    unsigned int v;
    asm volatile("global_load_dword %0, %1, off sc0 sc1\n\ts_waitcnt vmcnt(0)"
                 : "=v"(v) : "v"(p) : "memory");
    return v;
}

// ---------------- fp32 -> bf16 conversion ----------------
__global__ void cvt_f32_to_bf16(const float* __restrict__ src, short* __restrict__ dst, int n){
    int i = (blockIdx.x * blockDim.x + threadIdx.x) * 4;
    int stride = gridDim.x * blockDim.x * 4;
    for (; i + 3 < n; i += stride){
        float4 v = *(const float4*)(src + i);
        short4v o;
        o[0] = f2b(v.x); o[1] = f2b(v.y); o[2] = f2b(v.z); o[3] = f2b(v.w);
        *(short4v*)(dst + i) = o;
    }
}

// ---------------- gx chunk GEMM (m97-style 128x128 tile, bf16 out) ----------------
__global__ __launch_bounds__(256) void gx_gemm(
    const short* __restrict__ A,     // [T*B][K] bf16
    const short* __restrict__ W,     // [2*1536][K] bf16
    const float* __restrict__ bias,  // [2*1536] fp32
    short* __restrict__ gxc,         // [2][SCH*128][1536] bf16
    int K, int t0f, int t0b_lo)
{
    __shared__ __align__(16) short sA[4096];   // [128][32]
    __shared__ __align__(16) short sB[4096];
    const int dir = blockIdx.z;
    const int t0 = dir ? t0b_lo : t0f;
    const int m0 = blockIdx.x * 128;
    const int n0 = blockIdx.y * 128;
    const short* Ae = A + (size_t)(t0 * B_) * K;
    const short* We = W + (size_t)dir * G3 * K;
    short* out = gxc + (size_t)dir * ((size_t)SCH * B_ * G3);

    const int tid = threadIdx.x, wv = tid >> 6, lane = tid & 63;
    const int moff = (wv & 1) * 64, noff = (wv >> 1) * 64;
    const int e0 = wv * 1024 + lane * 8, e1 = e0 + 512;
    const short* a0 = Ae + (size_t)(m0 + (e0 >> 5)) * K + (e0 & 31);
    const short* a1 = Ae + (size_t)(m0 + (e1 >> 5)) * K + (e1 & 31);
    const short* b0 = We + (size_t)(n0 + (e0 >> 5)) * K + (e0 & 31);
    const short* b1 = We + (size_t)(n0 + (e1 >> 5)) * K + (e1 & 31);
    short* sa0 = &sA[wv * 1024];  short* sa1 = &sA[wv * 1024 + 512];
    short* sb0 = &sB[wv * 1024];  short* sb1 = &sB[wv * 1024 + 512];

    f32x4 acc[4][4] = {};
    const int lr = lane & 15, lk = (lane >> 4) * 8;

    for (int kk = 0; kk < K; kk += 32){
        gload16(a0 + kk, sa0); gload16(a1 + kk, sa1);
        gload16(b0 + kk, sb0); gload16(b1 + kk, sb1);
        __syncthreads();
        short8 ar[4], br[4];
        #pragma unroll
        for (int i = 0; i < 4; ++i) ar[i] = *(const short8*)&sA[(moff + i*16 + lr) * 32 + lk];
        #pragma unroll
        for (int i = 0; i < 4; ++i) br[i] = *(const short8*)&sB[(noff + i*16 + lr) * 32 + lk];
        #pragma unroll
        for (int ai = 0; ai < 4; ++ai)
            #pragma unroll
            for (int bi = 0; bi < 4; ++bi)
                acc[ai][bi] = __builtin_amdgcn_mfma_f32_16x16x32_bf16(ar[ai], br[bi], acc[ai][bi], 0, 0, 0);
        __syncthreads();
    }

    #pragma unroll
    for (int ai = 0; ai < 4; ++ai){
        #pragma unroll
        for (int bi = 0; bi < 4; ++bi){
            int col = n0 + noff + bi*16 + lr;
            float bv = bias[dir * G3 + col];
            #pragma unroll
            for (int r = 0; r < 4; ++r){
                int row = m0 + moff + ai*16 + ((lane >> 4) << 2) + r;
                out[(size_t)row * G3 + col] = f2b(acc[ai][bi][r] + bv);
            }
        }
    }
}

// ---------------- persistent chunk recurrence (per-producer incremental sync) -------
// grid (32, 2): blockIdx.x = ug*4+bg, dir = y. block 256 (4 waves).
// Wave wv: units [ug*64+wv*16,+16) x 3 gates; Whh slice resident (192 regs).
// Sync: per-producer flag words. Thread tid polls ONLY flag[tid&7] (no sleep) and
// stages ONLY that producer's 64-col block for row tid>>3 — each producer's h-load
// begins the moment that producer finishes; only the last straggler's load RT
// remains serial. xout store deferred until after the flag store (drain excludes it).
__global__ __launch_bounds__(256, 1) void rec_kernel(
    const short* __restrict__ gxc,        // [2][SCH*128][1536] bf16 (b_ih folded)
    const short* __restrict__ Whh,        // [2*1536][512] bf16
    const float* __restrict__ bhh,        // [2*1536] fp32
    short* __restrict__ xout,             // [T][B][1024] bf16
    float* __restrict__ hfm,              // [2][128][512] fp32 master (cross-launch)
    short* __restrict__ hbb,              // [2 parity][2 dir][128][512] bf16
    unsigned int* __restrict__ flags,     // per (dir,bg): 8 dwords, stride 32
    int t0f, int t0b_hi, int first, int base)
{
    __shared__ __align__(16) short lds_h[32 * 520];
    __shared__ __align__(16) short lds_out[32 * 72];
    const int tid = threadIdx.x, wv = tid >> 6, lane = tid & 63;
    const int ug = blockIdx.x >> 2, bg = blockIdx.x & 3, dir = blockIdx.y;
    const int u0w = ug * 64;
    const int u0 = u0w + wv * 16;
    const int m0 = bg * 32;
    const int lr = lane & 15, lk = (lane >> 4) * 8;
    const int crow = (lane >> 4) * 4;
    const int srow = tid >> 3;              // staging row 0..31
    const int pj   = tid & 7;               // my producer (unit-group) 0..7
    const int scol0 = pj * 8;               // repack column role

    // ---- resident weight fragments: 3 gates x 16 k-steps = 192 regs
    const short* Wd = Whh + (size_t)dir * G3 * H_;
    short8 wreg[3][16];
    #pragma unroll
    for (int g = 0; g < 3; ++g)
        #pragma unroll
        for (int kk = 0; kk < 16; ++kk)
            wreg[g][kk] = *(const short8*)&Wd[(size_t)(g*H_ + u0 + lr) * H_ + kk*32 + lk];

    float bh[3];
    #pragma unroll
    for (int g = 0; g < 3; ++g) bh[g] = bhh[dir*G3 + g*H_ + u0 + lr];

    float hreg[2][4];
    #pragma unroll
    for (int mt = 0; mt < 2; ++mt)
        #pragma unroll
        for (int r = 0; r < 4; ++r)
            hreg[mt][r] = first ? 0.f
                : hfm[((size_t)dir*B_ + m0 + mt*16 + crow + r)*H_ + u0 + lr];

    unsigned int* flg = flags + (dir*4 + bg) * 32;
    const short* gxd = gxc + (size_t)dir * ((size_t)SCH * B_ * G3);

    // prefetch gate inputs for step 0
    float gv[3][2][4];
    {
        const int tl0 = dir ? (SCH - 1) : 0;
        const short* gb = gxd + ((size_t)(tl0 * B_) + m0 + crow) * G3 + u0 + lr;
        #pragma unroll
        for (int g = 0; g < 3; ++g)
            #pragma unroll
            for (int mt = 0; mt < 2; ++mt)
                #pragma unroll
                for (int r = 0; r < 4; ++r)
                    gv[g][mt][r] = b2f(gb[(size_t)(mt*16 + r) * G3 + g * H_]);
    }

    for (int sl = 0; sl < SCH; ++sl){
        const int sg = base + sl;
        const int t  = dir ? (t0b_hi - sl) : (t0f + sl);
        const int rp = sg & 1;

        // ---- per-producer poll + incremental stage: wait for MY producer only,
        //      then load its 64-col block for my row (other threads proceed async)
        {
            while (poll_dw(flg + pj) < (unsigned int)sg) { }
            const short* hsrc = hbb + ((size_t)(rp*2 + dir) * B_ + m0 + srow) * H_ + pj*64;
            short8 hv[8];
            #pragma unroll
            for (int c = 0; c < 8; ++c)
                hv[c] = gload_sc(hsrc + c*8);
            wait_vm0();
            #pragma unroll
            for (int c = 0; c < 8; ++c)
                *(short8*)&lds_h[srow * 520 + pj*64 + c*8] = hv[c];
        }
        __syncthreads();

        // ---- recurrent GEMM from LDS, B resident
        f32x4 acc[3][2] = {};
        #pragma unroll
        for (int kk = 0; kk < 16; ++kk){
            short8 a0 = *(const short8*)&lds_h[(lr)      * 520 + kk*32 + lk];
            short8 a1 = *(const short8*)&lds_h[(16 + lr) * 520 + kk*32 + lk];
            #pragma unroll
            for (int g = 0; g < 3; ++g){
                acc[g][0] = __builtin_amdgcn_mfma_f32_16x16x32_bf16(a0, wreg[g][kk], acc[g][0], 0, 0, 0);
                acc[g][1] = __builtin_amdgcn_mfma_f32_16x16x32_bf16(a1, wreg[g][kk], acc[g][1], 0, 0, 0);
            }
        }

        // ---- gates + h update -> LDS out-tile (32 rows x 64 units)
        #pragma unroll
        for (int mt = 0; mt < 2; ++mt){
            #pragma unroll
            for (int r = 0; r < 4; ++r){
                float gr = acc[0][mt][r] + bh[0] + gv[0][mt][r];
                float gz = acc[1][mt][r] + bh[1] + gv[1][mt][r];
                float gn = acc[2][mt][r] + bh[2];
                float xn = gv[2][mt][r];
                float rg = 1.f / (1.f + __expf(-gr));
                float zg = 1.f / (1.f + __expf(-gz));
                float e2 = __expf(2.f * (xn + rg * gn));
                float ng = 1.f - 2.f / (e2 + 1.f);            // tanh, inf-safe
                float hn = (1.f - zg) * ng + zg * hreg[mt][r];
                hreg[mt][r] = hn;
                lds_out[(mt*16 + crow + r) * 72 + wv*16 + lr] = f2b(hn);
            }
        }
        __syncthreads();

        // ---- repack: ONE coalesced 16B sc-store to hbb; keep value for xout later
        short8 ov = *(const short8*)&lds_out[srow * 72 + scol0];
        {
            short* hwr = hbb + ((size_t)((rp^1)*2 + dir) * B_ + m0 + srow) * H_ + u0w + scol0;
            gstore16_sc(hwr, ov);
        }

        // ---- drain hbb stores only, then announce completion
        wait_vm0();
        __syncthreads();
        if (tid == 0) store_flag(&flg[ug], (unsigned int)(sg + 1));

        // ---- xout store off the critical path (after flag)
        *(short8*)&xout[((size_t)t * B_ + m0 + srow) * 1024 + dir*H_ + u0w + scol0] = ov;

        // ---- prefetch next step's gate inputs during peers' skew
        if (sl + 1 < SCH){
            const int tln = dir ? (SCH - 2 - sl) : (sl + 1);
            const short* gb = gxd + ((size_t)(tln * B_) + m0 + crow) * G3 + u0 + lr;
            #pragma unroll
            for (int g = 0; g < 3; ++g)
                #pragma unroll
                for (int mt = 0; mt < 2; ++mt)
                    #pragma unroll
                    for (int r = 0; r < 4; ++r)
                        gv[g][mt][r] = b2f(gb[(size_t)(mt*16 + r) * G3 + g * H_]);
        }
    }

    // persist fp32 master across chunk launches
    #pragma unroll
    for (int mt = 0; mt < 2; ++mt)
        #pragma unroll
        for (int r = 0; r < 4; ++r)
            hfm[((size_t)dir*B_ + m0 + mt*16 + crow + r)*H_ + u0 + lr] = hreg[mt][r];
}

// ---------------- final FC + sigmoid ----------------
__global__ void fc_kernel(const short* __restrict__ h, const float* __restrict__ w,
                          const float* __restrict__ b, float* __restrict__ out){
    int wid = threadIdx.x >> 6, lane = threadIdx.x & 63;
    int tb = blockIdx.x * 4 + wid;
    const short* hp = h + (size_t)tb * 1024 + lane * 16;
    float s = 0.f;
    #pragma unroll
    for (int c = 0; c < 2; ++c){
        short8 v = *(const short8*)(hp + c * 8);
        #pragma unroll
        for (int e = 0; e < 8; ++e) s += b2f(v[e]) * w[lane * 16 + c * 8 + e];
    }
    #pragma unroll
    for (int o = 32; o; o >>= 1) s += __shfl_down(s, o);
    if (lane == 0) out[tb] = 1.f / (1.f + __expf(-(s + b[0])));
}

extern "C" void kernel_launch(void* const* d_in, const int* in_sizes, int n_in,
                              void* d_out, int out_size, void* d_ws, size_t ws_size,
                              hipStream_t stream){
    const float* input_seq = (const float*)d_in[0];
    const float* W_ih0 = (const float*)d_in[1];
    const float* W_hh0 = (const float*)d_in[2];
    const float* b_ih0 = (const float*)d_in[3];
    const float* b_hh0 = (const float*)d_in[4];
    const float* W_ih  = (const float*)d_in[5];
    const float* W_hh  = (const float*)d_in[6];
    const float* b_ih  = (const float*)d_in[7];
    const float* b_hh  = (const float*)d_in[8];
    const float* fc_w  = (const float*)d_in[9];
    const float* fc_b  = (const float*)d_in[10];
    (void)in_sizes; (void)n_in; (void)out_size; (void)ws_size;

    char* ws = (char*)d_ws;
    size_t off = 0;
    auto alloc = [&](size_t bytes) -> char* {
        char* p = ws + off; off += (bytes + 255) & ~(size_t)255; return p;
    };
    short* actA = (short*)alloc((size_t)T_*B_*1024 * 2);          // 67.1 MB
    short* actB = (short*)alloc((size_t)T_*B_*1024 * 2);          // 67.1 MB
    short* gxc  = (short*)alloc((size_t)2*SCH*B_*G3 * 2);         // 25.2 MB
    short* wihl = (short*)alloc((size_t)2*G3*1024 * 2);           // 6.3 MB
    short* whhl = (short*)alloc((size_t)2*G3*H_ * 2);             // 3.1 MB
    float* hfm  = (float*)alloc((size_t)2*B_*H_ * 4);             // 0.5 MB
    short* hbb  = (short*)alloc((size_t)2*2*B_*H_ * 2);           // 0.5 MB
    unsigned int* bar = (unsigned int*)alloc(4096);

    auto cvt = [&](const float* s, short* d, size_t n){
        int blocks = (int)((n/4 + 255) / 256); if (blocks > 4096) blocks = 4096;
        hipLaunchKernelGGL(cvt_f32_to_bf16, dim3(blocks), dim3(256), 0, stream, s, d, (int)n);
    };

    // layer-0 input as [T*B][128] bf16 in actB's head
    cvt(input_seq, actB, (size_t)T_*B_*128);

    for (int l = 0; l < 5; ++l){
        const int K = l ? 1024 : 128;
        cvt(l ? W_ih + (size_t)(l-1)*2*G3*1024 : W_ih0, wihl, (size_t)2*G3*K);
        cvt(l ? W_hh + (size_t)(l-1)*2*G3*H_   : W_hh0, whhl, (size_t)2*G3*H_);
        const short* IN  = (l & 1) ? actA : actB;
        short*       OUT = (l & 1) ? actB : actA;
        const float* bi = l ? b_ih + (size_t)(l-1)*2*G3 : b_ih0;
        const float* bh = l ? b_hh + (size_t)(l-1)*2*G3 : b_hh0;

        hipMemsetAsync(hbb, 0, (size_t)2*2*B_*H_*2, stream);   // h(t=0)=0, both parities
        hipMemsetAsync(bar, 0, 4096, stream);                  // completion flags

        for (int q = 0; q < NCH; ++q){
            const int t0f    = SCH * q;
            const int t0b_hi = T_ - 1 - SCH * q;
            const int t0b_lo = t0b_hi - SCH + 1;
            hipLaunchKernelGGL(gx_gemm, dim3(SCH*B_/128, G3/128, 2), dim3(256), 0, stream,
                               IN, wihl, bi, gxc, K, t0f, t0b_lo);
            hipLaunchKernelGGL(rec_kernel, dim3(RWG, 2), dim3(256), 0, stream,
                               gxc, whhl, bh, OUT, hfm, hbb, bar, t0f, t0b_hi, q == 0, q*SCH);
        }
    }
    // layer 4 wrote actA
    hipLaunchKernelGGL(fc_kernel, dim3((T_*B_)/4), dim3(256), 0, stream,
                       actA, fc_w, fc_b, (float*)d_out);
}

// Round 16
// 5497.847 us; speedup vs baseline: 1.4038x; 1.4038x over previous
//
#include <hip/hip_runtime.h>
#include <hip/hip_bf16.h>

#define T_ 256
#define B_ 128
#define H_ 512
#define G3 1536
#define SCH 16      // timesteps per chunk
#define NCH 16      // chunks per layer
#define NGX 192     // gx WGs in fused launch (2 tile-jobs each, 384 jobs)

typedef __attribute__((ext_vector_type(8))) short short8;
typedef __attribute__((ext_vector_type(4))) short short4v;
typedef __attribute__((ext_vector_type(4))) float f32x4;
typedef __attribute__((ext_vector_type(4))) unsigned int uint4v;

static __device__ __forceinline__ float b2f(short s){
    unsigned u = ((unsigned)(unsigned short)s) << 16;
    return __builtin_bit_cast(float, u);
}
static __device__ __forceinline__ short f2b(float f){
    __hip_bfloat16 h = __float2bfloat16(f);   // RNE
    return __builtin_bit_cast(short, h);
}
static __device__ __forceinline__ void gload16(const void* g, void* l){
    __builtin_amdgcn_global_load_lds(
        (__attribute__((address_space(1))) void*)(void*)g,
        (__attribute__((address_space(3))) void*)l, 16, 0, 0);
}
static __device__ __forceinline__ void wait_vm0(){
    asm volatile("s_waitcnt vmcnt(0)" ::: "memory");
}
// device-coherent (MALL) ops — round-6-proven semantics
static __device__ __forceinline__ short8 gload_sc(const short* p){
    short8 v;
    asm volatile("global_load_dwordx4 %0, %1, off sc0 sc1"
                 : "=v"(v) : "v"(p) : "memory");
    return v;
}
static __device__ __forceinline__ void gstore16_sc(short* p, short8 v){
    asm volatile("global_store_dwordx4 %0, %1, off sc0 sc1"
                 :: "v"(p), "v"(v) : "memory");
}
static __device__ __forceinline__ void store_flag(unsigned int* p, unsigned int v){
    asm volatile("global_store_dword %0, %1, off sc0 sc1"
                 :: "v"(p), "v"(v) : "memory");
}
static __device__ __forceinline__ void load_flags8(const unsigned int* p, unsigned int* f){
    uint4v a, b;
    asm volatile("global_load_dwordx4 %0, %2, off sc0 sc1\n\t"
                 "global_load_dwordx4 %1, %3, off sc0 sc1\n\t"
                 "s_waitcnt vmcnt(0)"
                 : "=v"(a), "=v"(b) : "v"(p), "v"(p + 4) : "memory");
    f[0]=a.x; f[1]=a.y; f[2]=a.z; f[3]=a.w;
    f[4]=b.x; f[5]=b.y; f[6]=b.z; f[7]=b.w;
}

// ---------------- fp32 -> bf16 conversion ----------------
__global__ void cvt_f32_to_bf16(const float* __restrict__ src, short* __restrict__ dst, int n){
    int i = (blockIdx.x * blockDim.x + threadIdx.x) * 4;
    int stride = gridDim.x * blockDim.x * 4;
    for (; i + 3 < n; i += stride){
        float4 v = *(const float4*)(src + i);
        short4v o;
        o[0] = f2b(v.x); o[1] = f2b(v.y); o[2] = f2b(v.z); o[3] = f2b(v.w);
        *(short4v*)(dst + i) = o;
    }
}

// ---------------- gx 128x128 tile (m97-style), shared by standalone + fused ----------
static __device__ void gx_tile(const short* __restrict__ Ae,   // pre-offset by t0
                               const short* __restrict__ We,   // pre-offset by dir
                               const float* __restrict__ bias_d,
                               short* __restrict__ out,        // pre-offset by dir
                               int K, int m0, int n0, int tid,
                               short* sA, short* sB)
{
    const int wv = tid >> 6, lane = tid & 63;
    const int moff = (wv & 1) * 64, noff = (wv >> 1) * 64;
    const int e0 = wv * 1024 + lane * 8, e1 = e0 + 512;
    const short* a0 = Ae + (size_t)(m0 + (e0 >> 5)) * K + (e0 & 31);
    const short* a1 = Ae + (size_t)(m0 + (e1 >> 5)) * K + (e1 & 31);
    const short* b0 = We + (size_t)(n0 + (e0 >> 5)) * K + (e0 & 31);
    const short* b1 = We + (size_t)(n0 + (e1 >> 5)) * K + (e1 & 31);
    short* sa0 = &sA[wv * 1024];  short* sa1 = &sA[wv * 1024 + 512];
    short* sb0 = &sB[wv * 1024];  short* sb1 = &sB[wv * 1024 + 512];

    f32x4 acc[4][4] = {};
    const int lr = lane & 15, lk = (lane >> 4) * 8;

    for (int kk = 0; kk < K; kk += 32){
        gload16(a0 + kk, sa0); gload16(a1 + kk, sa1);
        gload16(b0 + kk, sb0); gload16(b1 + kk, sb1);
        __syncthreads();
        short8 ar[4], br[4];
        #pragma unroll
        for (int i = 0; i < 4; ++i) ar[i] = *(const short8*)&sA[(moff + i*16 + lr) * 32 + lk];
        #pragma unroll
        for (int i = 0; i < 4; ++i) br[i] = *(const short8*)&sB[(noff + i*16 + lr) * 32 + lk];
        #pragma unroll
        for (int ai = 0; ai < 4; ++ai)
            #pragma unroll
            for (int bi = 0; bi < 4; ++bi)
                acc[ai][bi] = __builtin_amdgcn_mfma_f32_16x16x32_bf16(ar[ai], br[bi], acc[ai][bi], 0, 0, 0);
        __syncthreads();
    }

    #pragma unroll
    for (int ai = 0; ai < 4; ++ai){
        #pragma unroll
        for (int bi = 0; bi < 4; ++bi){
            int col = n0 + noff + bi*16 + lr;
            float bv = bias_d[col];
            #pragma unroll
            for (int r = 0; r < 4; ++r){
                int row = m0 + moff + ai*16 + ((lane >> 4) << 2) + r;
                out[(size_t)row * G3 + col] = f2b(acc[ai][bi][r] + bv);
            }
        }
    }
}

// ---------------- standalone gx GEMM (layer prologue, chunk 0) ----------------
__global__ __launch_bounds__(256) void gx_gemm(
    const short* __restrict__ A, const short* __restrict__ W,
    const float* __restrict__ bias, short* __restrict__ gxc,
    int K, int t0f, int t0b_lo)
{
    __shared__ __align__(16) short sA[4096];
    __shared__ __align__(16) short sB[4096];
    const int dir = blockIdx.z;
    const int t0 = dir ? t0b_lo : t0f;
    gx_tile(A + (size_t)(t0 * B_) * K, W + (size_t)dir * G3 * K, bias + dir * G3,
            gxc + (size_t)dir * ((size_t)SCH * B_ * G3),
            K, blockIdx.x * 128, blockIdx.y * 128, threadIdx.x, sA, sB);
}

// ---------------- fused: rec(chunk q) on blocks 0..63 + gx(chunk q+1) on 64..255 ----
// LDS padded to 80KB -> exactly 1 block/CU -> rec WGs get DEDICATED CUs (round-12
// fix #1); h exchange via small MALL-resident hbb (round-12 fix #2). rec = round-14
// chassis with all-waves uniform flag polling (no tid0 funnel, no pre-load barrier).
// gx blocks never wait on anything -> no deadlock; 2 tile-jobs each.
__global__ __launch_bounds__(256, 1) void fused_step(
    const short* __restrict__ gxc_cur,  // this chunk's gate inputs
    const short* __restrict__ IN,       // layer input (gx part)
    const short* __restrict__ Wih,      // [2*1536][K] (gx part)
    const float* __restrict__ bih,      // [2*1536] (gx part)
    short* __restrict__ gxc_nxt,        // next chunk's gate inputs (gx out)
    const short* __restrict__ Whh,      // [2*1536][512]
    const float* __restrict__ bhh,      // [2*1536]
    short* __restrict__ xout,           // [T][B][1024]
    float* __restrict__ hfm,            // [2][128][512] fp32 master
    short* __restrict__ hbb,            // [2 parity][2 dir][128][512] bf16
    unsigned int* __restrict__ flags,   // per (dir,bg): 8 dwords, stride 32
    int K, int t0f_n, int t0b_lo_n, int base, int first)
{
    __shared__ __align__(16) char smem[81920];   // pad to force 1 block/CU
    const int tid = threadIdx.x;
    const int bid = blockIdx.x;

    if (bid >= 64){
        short* sA = (short*)smem;
        short* sB = (short*)(smem + 8192);
        for (int job = bid - 64; job < 384; job += NGX){
            const int mi = job & 15, ni = (job >> 4) % 12, dr = job / 192;
            const int t0 = dr ? t0b_lo_n : t0f_n;
            gx_tile(IN + (size_t)(t0 * B_) * K, Wih + (size_t)dr * G3 * K, bih + dr * G3,
                    gxc_nxt + (size_t)dr * ((size_t)SCH * B_ * G3),
                    K, mi * 128, ni * 128, tid, sA, sB);
        }
        return;
    }

    // ---------------- rec part (round-14 chassis) ----------------
    short* lds_h   = (short*)smem;                 // 32 x 520 shorts
    short* lds_out = (short*)(smem + 33280);       // 32 x 72 shorts
    const int wv = tid >> 6, lane = tid & 63;
    const int ug = bid >> 3, gid = bid & 7;
    const int dir = gid >> 2, bg = gid & 3;
    const int u0w = ug * 64;
    const int u0 = u0w + wv * 16;
    const int m0 = bg * 32;
    const int lr = lane & 15, lk = (lane >> 4) * 8;
    const int crow = (lane >> 4) * 4;
    const int srow = tid >> 3, scol0 = (tid & 7) * 8;
    const int t0f = base, t0b_hi = T_ - 1 - base;

    const short* Wd = Whh + (size_t)dir * G3 * H_;
    short8 wreg[3][16];
    #pragma unroll
    for (int g = 0; g < 3; ++g)
        #pragma unroll
        for (int kk = 0; kk < 16; ++kk)
            wreg[g][kk] = *(const short8*)&Wd[(size_t)(g*H_ + u0 + lr) * H_ + kk*32 + lk];

    float bh[3];
    #pragma unroll
    for (int g = 0; g < 3; ++g) bh[g] = bhh[dir*G3 + g*H_ + u0 + lr];

    float hreg[2][4];
    #pragma unroll
    for (int mt = 0; mt < 2; ++mt)
        #pragma unroll
        for (int r = 0; r < 4; ++r)
            hreg[mt][r] = first ? 0.f
                : hfm[((size_t)dir*B_ + m0 + mt*16 + crow + r)*H_ + u0 + lr];

    unsigned int* flg = flags + (dir*4 + bg) * 32;
    const short* gxd = gxc_cur + (size_t)dir * ((size_t)SCH * B_ * G3);

    float gv[3][2][4];
    {
        const int tl0 = dir ? (SCH - 1) : 0;
        const short* gb = gxd + ((size_t)(tl0 * B_) + m0 + crow) * G3 + u0 + lr;
        #pragma unroll
        for (int g = 0; g < 3; ++g)
            #pragma unroll
            for (int mt = 0; mt < 2; ++mt)
                #pragma unroll
                for (int r = 0; r < 4; ++r)
                    gv[g][mt][r] = b2f(gb[(size_t)(mt*16 + r) * G3 + g * H_]);
    }

    for (int sl = 0; sl < SCH; ++sl){
        const int sg = base + sl;
        const int t  = dir ? (t0b_hi - sl) : (t0f + sl);
        const int rp = sg & 1;

        // ---- ALL waves poll the 8-flag line (wave-coalesced); proceed directly
        {
            unsigned int f[8];
            for (;;){
                load_flags8(flg, f);
                bool ok = true;
                #pragma unroll
                for (int j = 0; j < 8; ++j) ok &= (f[j] >= (unsigned int)sg);
                if (ok) break;
            }
        }

        // ---- stage h[rp][dir] tile into LDS (each thread verified readiness itself)
        {
            const short* hsrc = hbb + ((size_t)(rp*2 + dir) * B_ + m0) * H_;
            short8 hv[8];
            #pragma unroll
            for (int c = 0; c < 8; ++c)
                hv[c] = gload_sc(hsrc + (size_t)srow * H_ + scol0 + c*64);
            wait_vm0();
            #pragma unroll
            for (int c = 0; c < 8; ++c)
                *(short8*)&lds_h[srow * 520 + scol0 + c*64] = hv[c];
        }
        __syncthreads();

        // ---- recurrent GEMM from LDS, B resident
        f32x4 acc[3][2] = {};
        #pragma unroll
        for (int kk = 0; kk < 16; ++kk){
            short8 a0 = *(const short8*)&lds_h[(lr)      * 520 + kk*32 + lk];
            short8 a1 = *(const short8*)&lds_h[(16 + lr) * 520 + kk*32 + lk];
            #pragma unroll
            for (int g = 0; g < 3; ++g){
                acc[g][0] = __builtin_amdgcn_mfma_f32_16x16x32_bf16(a0, wreg[g][kk], acc[g][0], 0, 0, 0);
                acc[g][1] = __builtin_amdgcn_mfma_f32_16x16x32_bf16(a1, wreg[g][kk], acc[g][1], 0, 0, 0);
            }
        }

        // ---- gates + h update -> LDS out-tile
        #pragma unroll
        for (int mt = 0; mt < 2; ++mt){
            #pragma unroll
            for (int r = 0; r < 4; ++r){
                float gr = acc[0][mt][r] + bh[0] + gv[0][mt][r];
                float gz = acc[1][mt][r] + bh[1] + gv[1][mt][r];
                float gn = acc[2][mt][r] + bh[2];
                float xn = gv[2][mt][r];
                float rg = 1.f / (1.f + __expf(-gr));
                float zg = 1.f / (1.f + __expf(-gz));
                float e2 = __expf(2.f * (xn + rg * gn));
                float ng = 1.f - 2.f / (e2 + 1.f);            // tanh, inf-safe
                float hn = (1.f - zg) * ng + zg * hreg[mt][r];
                hreg[mt][r] = hn;
                lds_out[(mt*16 + crow + r) * 72 + wv*16 + lr] = f2b(hn);
            }
        }
        __syncthreads();

        // ---- repack: ONE coalesced 16B sc-store to hbb
        short8 ov = *(const short8*)&lds_out[srow * 72 + scol0];
        {
            short* hwr = hbb + ((size_t)((rp^1)*2 + dir) * B_ + m0 + srow) * H_ + u0w + scol0;
            gstore16_sc(hwr, ov);
        }

        // ---- drain hbb stores only, then announce completion
        wait_vm0();
        __syncthreads();
        if (tid == 0) store_flag(&flg[ug], (unsigned int)(sg + 1));

        // ---- xout store off the critical path (after flag)
        *(short8*)&xout[((size_t)t * B_ + m0 + srow) * 1024 + dir*H_ + u0w + scol0] = ov;

        // ---- prefetch next step's gate inputs during peers' skew
        if (sl + 1 < SCH){
            const int tln = dir ? (SCH - 2 - sl) : (sl + 1);
            const short* gb = gxd + ((size_t)(tln * B_) + m0 + crow) * G3 + u0 + lr;
            #pragma unroll
            for (int g = 0; g < 3; ++g)
                #pragma unroll
                for (int mt = 0; mt < 2; ++mt)
                    #pragma unroll
                    for (int r = 0; r < 4; ++r)
                        gv[g][mt][r] = b2f(gb[(size_t)(mt*16 + r) * G3 + g * H_]);
        }
    }

    // persist fp32 master across chunk launches
    #pragma unroll
    for (int mt = 0; mt < 2; ++mt)
        #pragma unroll
        for (int r = 0; r < 4; ++r)
            hfm[((size_t)dir*B_ + m0 + mt*16 + crow + r)*H_ + u0 + lr] = hreg[mt][r];
}

// ---------------- final FC + sigmoid ----------------
__global__ void fc_kernel(const short* __restrict__ h, const float* __restrict__ w,
                          const float* __restrict__ b, float* __restrict__ out){
    int wid = threadIdx.x >> 6, lane = threadIdx.x & 63;
    int tb = blockIdx.x * 4 + wid;
    const short* hp = h + (size_t)tb * 1024 + lane * 16;
    float s = 0.f;
    #pragma unroll
    for (int c = 0; c < 2; ++c){
        short8 v = *(const short8*)(hp + c * 8);
        #pragma unroll
        for (int e = 0; e < 8; ++e) s += b2f(v[e]) * w[lane * 16 + c * 8 + e];
    }
    #pragma unroll
    for (int o = 32; o; o >>= 1) s += __shfl_down(s, o);
    if (lane == 0) out[tb] = 1.f / (1.f + __expf(-(s + b[0])));
}

extern "C" void kernel_launch(void* const* d_in, const int* in_sizes, int n_in,
                              void* d_out, int out_size, void* d_ws, size_t ws_size,
                              hipStream_t stream){
    const float* input_seq = (const float*)d_in[0];
    const float* W_ih0 = (const float*)d_in[1];
    const float* W_hh0 = (const float*)d_in[2];
    const float* b_ih0 = (const float*)d_in[3];
    const float* b_hh0 = (const float*)d_in[4];
    const float* W_ih  = (const float*)d_in[5];
    const float* W_hh  = (const float*)d_in[6];
    const float* b_ih  = (const float*)d_in[7];
    const float* b_hh  = (const float*)d_in[8];
    const float* fc_w  = (const float*)d_in[9];
    const float* fc_b  = (const float*)d_in[10];
    (void)in_sizes; (void)n_in; (void)out_size; (void)ws_size;

    char* ws = (char*)d_ws;
    size_t off = 0;
    auto alloc = [&](size_t bytes) -> char* {
        char* p = ws + off; off += (bytes + 255) & ~(size_t)255; return p;
    };
    short* actA = (short*)alloc((size_t)T_*B_*1024 * 2);          // 67.1 MB
    short* actB = (short*)alloc((size_t)T_*B_*1024 * 2);          // 67.1 MB
    short* gxc0 = (short*)alloc((size_t)2*SCH*B_*G3 * 2);         // 12.6 MB
    short* gxc1 = (short*)alloc((size_t)2*SCH*B_*G3 * 2);         // 12.6 MB
    short* wihl = (short*)alloc((size_t)2*G3*1024 * 2);           // 6.3 MB
    short* whhl = (short*)alloc((size_t)2*G3*H_ * 2);             // 3.1 MB
    float* hfm  = (float*)alloc((size_t)2*B_*H_ * 4);             // 0.5 MB
    short* hbb  = (short*)alloc((size_t)2*2*B_*H_ * 2);           // 0.5 MB
    unsigned int* bar = (unsigned int*)alloc(4096);

    auto cvt = [&](const float* s, short* d, size_t n){
        int blocks = (int)((n/4 + 255) / 256); if (blocks > 4096) blocks = 4096;
        hipLaunchKernelGGL(cvt_f32_to_bf16, dim3(blocks), dim3(256), 0, stream, s, d, (int)n);
    };

    // layer-0 input as [T*B][128] bf16 in actB's head
    cvt(input_seq, actB, (size_t)T_*B_*128);

    short* gxbuf[2] = { gxc0, gxc1 };

    for (int l = 0; l < 5; ++l){
        const int K = l ? 1024 : 128;
        cvt(l ? W_ih + (size_t)(l-1)*2*G3*1024 : W_ih0, wihl, (size_t)2*G3*K);
        cvt(l ? W_hh + (size_t)(l-1)*2*G3*H_   : W_hh0, whhl, (size_t)2*G3*H_);
        const short* IN  = (l & 1) ? actA : actB;
        short*       OUT = (l & 1) ? actB : actA;
        const float* bi = l ? b_ih + (size_t)(l-1)*2*G3 : b_ih0;
        const float* bh = l ? b_hh + (size_t)(l-1)*2*G3 : b_hh0;

        hipMemsetAsync(hbb, 0, (size_t)2*2*B_*H_*2, stream);   // h(t=0)=0, both parities
        hipMemsetAsync(bar, 0, 4096, stream);                  // completion flags

        // chunk 0's gate inputs (prologue)
        hipLaunchKernelGGL(gx_gemm, dim3(SCH*B_/128, G3/128, 2), dim3(256), 0, stream,
                           IN, wihl, bi, gxbuf[0], K, 0, T_ - SCH);

        for (int q = 0; q < NCH; ++q){
            const int has_gx = (q < NCH - 1);
            hipLaunchKernelGGL(fused_step, dim3(64 + (has_gx ? NGX : 0)), dim3(256), 0, stream,
                               gxbuf[q & 1], IN, wihl, bi, gxbuf[(q + 1) & 1],
                               whhl, bh, OUT, hfm, hbb, bar,
                               K, (q + 1) * SCH, T_ - (q + 2) * SCH,
                               q * SCH, q == 0);
        }
    }
    // layer 4 wrote actA
    hipLaunchKernelGGL(fc_kernel, dim3((T_*B_)/4), dim3(256), 0, stream,
                       actA, fc_w, fc_b, (float*)d_out);
}